// Round 2
// baseline (140.750 us; speedup 1.0000x reference)
//
#include <hip/hip_runtime.h>
#include <hip/hip_bf16.h>

typedef float f32x4 __attribute__((ext_vector_type(4)));
typedef __bf16 bf16x8 __attribute__((ext_vector_type(8)));

constexpr int B2     = 512;
constexpr int KDIM   = 65536;   // 256*16*16
constexpr int BM     = 256;
constexpr int BK     = 64;
constexpr int NSTEPS = KDIM / BK;   // 1024
constexpr int NTILES = 3;           // (0,0),(0,1),(1,1) — Gram symmetry
constexpr int KSPLIT = 85;
constexpr int NBLK   = NTILES * KSPLIT;  // 255

// ---- fp32 -> packed 2x bf16 (RNE) ----
__device__ __forceinline__ unsigned pack_bf16x2(float a, float b) {
    __bf16 ha = (__bf16)a, hb = (__bf16)b;
    unsigned short ua, ub;
    __builtin_memcpy(&ua, &ha, 2);
    __builtin_memcpy(&ub, &hb, 2);
    return (unsigned)ua | ((unsigned)ub << 16);
}

// issue 8 float4 global loads (one 256x64 fp32 tile, this thread's share)
__device__ __forceinline__ void issue_loads(float4* dst, const float* __restrict__ src,
                                            int k0, int tid) {
#pragma unroll
    for (int it = 0; it < 8; ++it) {
        int r = it * 32 + (tid >> 4);
        dst[it] = *reinterpret_cast<const float4*>(src + (size_t)r * KDIM + k0 + (tid & 15) * 4);
    }
}

// convert + XOR-swizzled ds_write (same XOR on the read side)
__device__ __forceinline__ void convert_store(__bf16* lds, const float4* v, int tid) {
#pragma unroll
    for (int it = 0; it < 8; ++it) {
        int r = it * 32 + (tid >> 4);
        unsigned lo = pack_bf16x2(v[it].x, v[it].y);
        unsigned hi = pack_bf16x2(v[it].z, v[it].w);
        int byte = (r * 128 + (tid & 15) * 8) ^ ((r & 7) << 4);
        *reinterpret_cast<uint2*>(reinterpret_cast<char*>(lds) + byte) = make_uint2(lo, hi);
    }
}

__global__ __launch_bounds__(512, 2) void gemm_partial(const float* __restrict__ X,
                                                       float* __restrict__ partials) {
    __shared__ __align__(16) __bf16 ldsA[2][BM * BK];   // 64 KB
    __shared__ __align__(16) __bf16 ldsB[2][BM * BK];   // 64 KB

    // Bijective chunked XCD swizzle (255 blocks, 8 XCDs: chunks 32x7 + 31):
    // order blocks split-major so the 3 tiles of one split share an XCD's L2.
    int d    = blockIdx.x;
    int xcd  = d & 7, slot = d >> 3;
    int L    = (xcd < 7 ? xcd * 32 : 224) + slot;
    int split = L / 3;
    int tile  = L - split * 3;           // 0:(0,0) 1:(0,1) 2:(1,1)

    int ti = (tile == 2) ? 1 : 0;
    int tj = (tile == 0) ? 0 : 1;
    bool diag = (ti == tj);
    const float* Abase = X + (size_t)ti * 256 * KDIM;
    const float* Bbase = X + (size_t)tj * 256 * KDIM;

    int tid  = threadIdx.x;
    int lane = tid & 63;
    int wave = tid >> 6;     // 8 waves: 2 (M) x 4 (N)
    int wr = wave >> 2;
    int wc = wave & 3;

    int s0 = split * NSTEPS / KSPLIT;
    int s1 = (split + 1) * NSTEPS / KSPLIT;

    f32x4 acc[8][4] = {};
    float4 pa[8], pb[8];

    // prologue: stage K-chunk s0 into buffer 0
    issue_loads(pa, Abase, s0 * BK, tid);
    if (!diag) issue_loads(pb, Bbase, s0 * BK, tid);
    convert_store(ldsA[0], pa, tid);
    if (!diag) convert_store(ldsB[0], pb, tid);
    __syncthreads();

    int cur = 0;
    for (int s = s0; s < s1; ++s) {
        bool more = (s + 1 < s1);
        // T14 issue-early: next chunk's loads go in flight under this chunk's MFMAs
        if (more) {
            issue_loads(pa, Abase, (s + 1) * BK, tid);
            if (!diag) issue_loads(pb, Bbase, (s + 1) * BK, tid);
        }

        const char* bufA = (const char*)ldsA[cur];
        const char* bufB = diag ? bufA : (const char*)ldsB[cur];

#pragma unroll
        for (int kk = 0; kk < 2; ++kk) {
            int kbyte = kk * 64 + (lane >> 4) * 16;
            bf16x8 bfr[4];
#pragma unroll
            for (int ni = 0; ni < 4; ++ni) {
                int row = wc * 64 + ni * 16 + (lane & 15);
                bfr[ni] = *reinterpret_cast<const bf16x8*>(
                    bufB + ((row * 128 + kbyte) ^ ((row & 7) << 4)));
            }
#pragma unroll
            for (int mi = 0; mi < 8; ++mi) {
                int row = wr * 128 + mi * 16 + (lane & 15);
                bf16x8 a = *reinterpret_cast<const bf16x8*>(
                    bufA + ((row * 128 + kbyte) ^ ((row & 7) << 4)));
#pragma unroll
                for (int ni = 0; ni < 4; ++ni)
                    acc[mi][ni] = __builtin_amdgcn_mfma_f32_16x16x32_bf16(
                        a, bfr[ni], acc[mi][ni], 0, 0, 0);
            }
        }

        // write-late into the other buffer; one barrier per K-step
        if (more) {
            convert_store(ldsA[cur ^ 1], pa, tid);
            if (!diag) convert_store(ldsB[cur ^ 1], pb, tid);
        }
        __syncthreads();
        cur ^= 1;
    }

    float* out = partials + (size_t)(tile * KSPLIT + split) * (BM * BM);
    int col   = lane & 15;
    int rquad = (lane >> 4) * 4;
#pragma unroll
    for (int mi = 0; mi < 8; ++mi) {
#pragma unroll
        for (int ni = 0; ni < 4; ++ni) {
            int j = wc * 64 + ni * 16 + col;
#pragma unroll
            for (int v = 0; v < 4; ++v) {
                int i = wr * 128 + mi * 16 + rquad + v;
                out[i * BM + j] = acc[mi][ni][v];
            }
        }
    }
}

// fold split-K partials into full 512x512 C (float4, mirror the off-diag tile)
__global__ __launch_bounds__(256) void reduce_partials(const float* __restrict__ partials,
                                                       float* __restrict__ C) {
    int idx  = blockIdx.x * 256 + threadIdx.x;   // over 3*16384 float4s
    int tile = idx / 16384;
    int e4   = idx & 16383;
    const float4* p = reinterpret_cast<const float4*>(
                          partials + (size_t)tile * KSPLIT * 65536) + e4;
    float4 sum = make_float4(0.f, 0.f, 0.f, 0.f);
    for (int s = 0; s < KSPLIT; ++s) {
        float4 v = p[(size_t)s * 16384];
        sum.x += v.x; sum.y += v.y; sum.z += v.z; sum.w += v.w;
    }
    int e = e4 * 4;
    int i = e >> 8, j = e & 255;
    int gi = (tile == 2) ? 256 + i : i;
    int gj = (tile == 0) ? j : 256 + j;
    *reinterpret_cast<float4*>(C + gi * 512 + gj) = sum;
    if (tile == 1) {
        C[(gj + 0) * 512 + gi] = sum.x;
        C[(gj + 1) * 512 + gi] = sum.y;
        C[(gj + 2) * 512 + gi] = sum.z;
        C[(gj + 3) * 512 + gi] = sum.w;
    }
}

// loss = mean( clip(sq_i + sq_j - 2*C_ij, 1e-12) * mask(i,j)^2 )
__global__ __launch_bounds__(256) void loss_kernel(const float* __restrict__ C,
                                                   const int* __restrict__ ranking,
                                                   const int* __restrict__ choice,
                                                   const int* __restrict__ ncp,
                                                   float* __restrict__ out) {
    __shared__ int pos[16];
    __shared__ float wsum[4];
    int i   = blockIdx.x;
    int tid = threadIdx.x;
    if (tid < 16) pos[ranking[i * 16 + tid]] = tid;
    __syncthreads();

    float nc  = (float)(*ncp);
    int   ci  = choice[i];
    float c   = (float)ci;
    float sqi = C[i * 513];   // C[i][i]
    float sum = 0.f;

    for (int j = tid; j < B2; j += 256) {
        int   lbl = ranking[j * 16];        // labels[j] = ranking[j][0]
        int   r   = pos[lbl];               // rank_of_label[i][j]
        float sqj = C[j * 513];
        float d2  = sqi + sqj - 2.f * C[i * 512 + j];
        d2 = fmaxf(d2, 1e-12f);
        float jf = (float)r;
        float m  = (r < ci) ? (1.f - jf / c) : (-(jf - c + 1.f) / (nc - c));
        sum += d2 * m * m;
    }

    for (int off = 32; off > 0; off >>= 1) sum += __shfl_down(sum, off);
    int lane = tid & 63, wave = tid >> 6;
    if (lane == 0) wsum[wave] = sum;
    __syncthreads();
    if (tid == 0) {
        float t = wsum[0] + wsum[1] + wsum[2] + wsum[3];
        atomicAdd(out, t * (1.f / ((float)B2 * (float)B2)));
    }
}

extern "C" void kernel_launch(void* const* d_in, const int* in_sizes, int n_in,
                              void* d_out, int out_size, void* d_ws, size_t ws_size,
                              hipStream_t stream) {
    const float* X       = (const float*)d_in[0];
    const int*   ranking = (const int*)d_in[1];
    const int*   choice  = (const int*)d_in[2];
    const int*   ncp     = (const int*)d_in[3];
    float*       out     = (float*)d_out;
    float*       ws      = (float*)d_ws;

    // ws layout: C (512*512 f32 = 1 MB) | partials (255 * 256 KB = 65 MB)
    float* C        = ws;
    float* partials = ws + 262144;

    hipMemsetAsync(d_out, 0, sizeof(float), stream);

    gemm_partial<<<dim3(NBLK), dim3(512), 0, stream>>>(X, partials);
    reduce_partials<<<dim3(NTILES * 16384 / 256), dim3(256), 0, stream>>>(partials, C);
    loss_kernel<<<dim3(B2), dim3(256), 0, stream>>>(C, ranking, choice, ncp, out);
}

// Round 3
// 68.005 us; speedup vs baseline: 2.0697x; 2.0697x over previous
//
#include <hip/hip_runtime.h>
#include <hip/hip_bf16.h>

typedef float f32x4 __attribute__((ext_vector_type(4)));
typedef __bf16 bf16x8 __attribute__((ext_vector_type(8)));

constexpr int B2     = 512;
constexpr int KDIM   = 65536;     // 256*16*16
constexpr int BM     = 256;
constexpr int BK     = 32;
constexpr int NK     = KDIM / BK; // 2048 K-steps
constexpr int KSPLIT = 85;
constexpr int NBLK   = 3 * KSPLIT; // 255

// async 16B global->LDS (no VGPR round trip); LDS dest = wave-uniform base + lane*16
__device__ __forceinline__ void gload16(const void* g, void* l) {
    __builtin_amdgcn_global_load_lds(
        (__attribute__((address_space(1))) void*)(g),
        (__attribute__((address_space(3))) void*)(l), 16, 0, 0);
}

// Stage one 256x32 fp32 panel into LDS, linear dest, XOR-swizzled SOURCE:
// LDS slot (r, s) holds global 16B slot (s ^ (r&7)) of row r.  Row stride 128B.
__device__ __forceinline__ void stage_panel(const float* __restrict__ src, int k0,
                                            float* ldsPanel, int tid) {
#pragma unroll
    for (int i = 0; i < 4; ++i) {
        int r    = i * 64 + (tid >> 3);
        int slot = (tid & 7) ^ (r & 7);
        const float* g = src + (size_t)r * KDIM + k0 + slot * 4;
        char* l = (char*)ldsPanel + i * 8192 + (tid & ~63) * 16;  // wave-uniform base
        gload16(g, l);
    }
}

// read 8 consecutive fp32 (k-slice) from swizzled fp32 tile, convert to bf16x8
__device__ __forceinline__ bf16x8 read_frag(const char* base, int rowByte, int s0b, int s1b) {
    f32x4 lo = *reinterpret_cast<const f32x4*>(base + rowByte + s0b);
    f32x4 hi = *reinterpret_cast<const f32x4*>(base + rowByte + s1b);
    bf16x8 r;
    r[0] = (__bf16)lo[0]; r[1] = (__bf16)lo[1]; r[2] = (__bf16)lo[2]; r[3] = (__bf16)lo[3];
    r[4] = (__bf16)hi[0]; r[5] = (__bf16)hi[1]; r[6] = (__bf16)hi[2]; r[7] = (__bf16)hi[3];
    return r;
}

__global__ __launch_bounds__(512, 2) void gemm_partial(const float* __restrict__ X,
                                                       __bf16* __restrict__ partials) {
    __shared__ __align__(16) float ldsT[2][2][BM * BK];   // [dbuf][panel] = 128 KB

    // bijective chunked XCD swizzle: split-major so one split's 3 tiles share an XCD L2
    int d = blockIdx.x;
    int xcd = d & 7, slotb = d >> 3;
    int L = (xcd < 7 ? xcd * 32 : 224) + slotb;
    int split = L / 3;
    int tile  = L - split * 3;            // 0:(0,0) 1:(0,1) 2:(1,1)

    int ti = (tile == 2) ? 1 : 0;
    int tj = (tile == 0) ? 0 : 1;
    bool diag = (ti == tj);
    const float* Abase = X + (size_t)ti * 256 * KDIM;
    const float* Bbase = X + (size_t)tj * 256 * KDIM;

    int tid  = threadIdx.x;
    int lane = tid & 63;
    int wave = tid >> 6;       // 8 waves: 2(M) x 4(N)
    int wr = wave >> 2, wc = wave & 3;

    int s0 = split * NK / KSPLIT;
    int s1 = (split + 1) * NK / KSPLIT;

    f32x4 acc[8][4] = {};

    // lane's two swizzled 16B-slot byte offsets for its k-slice (row&7 == lane&7 for all frags)
    int q  = lane >> 4;
    int rx = lane & 7;
    int s0b = ((2 * q)     ^ rx) * 16;
    int s1b = ((2 * q + 1) ^ rx) * 16;

    // prologue
    stage_panel(Abase, s0 * BK, &ldsT[0][0][0], tid);
    if (!diag) stage_panel(Bbase, s0 * BK, &ldsT[0][1][0], tid);
    __syncthreads();   // drains vmcnt(0)

    int cur = 0;
    for (int s = s0; s < s1; ++s) {
        // T3 2-phase: issue next tile's async loads FIRST (in flight across MFMA phase)
        if (s + 1 < s1) {
            stage_panel(Abase, (s + 1) * BK, &ldsT[cur ^ 1][0][0], tid);
            if (!diag) stage_panel(Bbase, (s + 1) * BK, &ldsT[cur ^ 1][1][0], tid);
        }

        const char* bA = (const char*)&ldsT[cur][0][0];
        const char* bB = diag ? bA : (const char*)&ldsT[cur][1][0];

        bf16x8 bfr[4];
#pragma unroll
        for (int ni = 0; ni < 4; ++ni) {
            int rowB = wc * 64 + ni * 16 + (lane & 15);
            bfr[ni] = read_frag(bB, rowB * 128, s0b, s1b);
        }
#pragma unroll
        for (int mi = 0; mi < 8; ++mi) {
            int rowA = wr * 128 + mi * 16 + (lane & 15);
            bf16x8 a = read_frag(bA, rowA * 128, s0b, s1b);
#pragma unroll
            for (int ni = 0; ni < 4; ++ni)
                acc[mi][ni] = __builtin_amdgcn_mfma_f32_16x16x32_bf16(
                    a, bfr[ni], acc[mi][ni], 0, 0, 0);
        }

        __syncthreads();   // vmcnt(0)+barrier: next buffer staged, this one free
        cur ^= 1;
    }

    // epilogue: bf16 partial tile (halves partial traffic; error ~0.05% << 2.6% budget)
    __bf16* out = partials + (size_t)(tile * KSPLIT + split) * (BM * BM);
    int col = lane & 15, rquad = (lane >> 4) * 4;
#pragma unroll
    for (int mi = 0; mi < 8; ++mi)
#pragma unroll
        for (int ni = 0; ni < 4; ++ni) {
            int j = wc * 64 + ni * 16 + col;
#pragma unroll
            for (int v = 0; v < 4; ++v) {
                int i = wr * 128 + mi * 16 + rquad + v;
                out[i * BM + j] = (__bf16)acc[mi][ni][v];
            }
        }
}

__global__ __launch_bounds__(256) void reduce_partials(const __bf16* __restrict__ partials,
                                                       float* __restrict__ C) {
    int idx  = blockIdx.x * 256 + threadIdx.x;   // over 3*16384 groups of 4
    int tile = idx / 16384;
    int e4   = idx & 16383;
    const __bf16* p = partials + (size_t)tile * KSPLIT * 65536 + e4 * 4;
    float sx = 0.f, sy = 0.f, sz = 0.f, sw = 0.f;
    for (int s = 0; s < KSPLIT; ++s) {
        ushort4 v = *reinterpret_cast<const ushort4*>(p + (size_t)s * 65536);
        union { unsigned u; float f; } a, b, c2, d2;
        a.u  = (unsigned)v.x << 16;  b.u  = (unsigned)v.y << 16;
        c2.u = (unsigned)v.z << 16;  d2.u = (unsigned)v.w << 16;
        sx += a.f; sy += b.f; sz += c2.f; sw += d2.f;
    }
    int e = e4 * 4;
    int i = e >> 8, j = e & 255;
    int gi = (tile == 2) ? 256 + i : i;
    int gj = (tile == 0) ? j : 256 + j;
    float4 sum = make_float4(sx, sy, sz, sw);
    *reinterpret_cast<float4*>(C + gi * 512 + gj) = sum;
    if (tile == 1) {
        C[(gj + 0) * 512 + gi] = sum.x;
        C[(gj + 1) * 512 + gi] = sum.y;
        C[(gj + 2) * 512 + gi] = sum.z;
        C[(gj + 3) * 512 + gi] = sum.w;
    }
}

// loss = mean( clip(sq_i + sq_j - 2*C_ij, 1e-12) * mask(i,j)^2 )
__global__ __launch_bounds__(256) void loss_kernel(const float* __restrict__ C,
                                                   const int* __restrict__ ranking,
                                                   const int* __restrict__ choice,
                                                   const int* __restrict__ ncp,
                                                   float* __restrict__ out) {
    __shared__ int pos[16];
    __shared__ float wsum[4];
    int i   = blockIdx.x;
    int tid = threadIdx.x;
    if (tid < 16) pos[ranking[i * 16 + tid]] = tid;
    __syncthreads();

    float nc  = (float)(*ncp);
    int   ci  = choice[i];
    float c   = (float)ci;
    float sqi = C[i * 513];
    float sum = 0.f;

    for (int j = tid; j < B2; j += 256) {
        int   lbl = ranking[j * 16];
        int   r   = pos[lbl];
        float sqj = C[j * 513];
        float d2  = sqi + sqj - 2.f * C[i * 512 + j];
        d2 = fmaxf(d2, 1e-12f);
        float jf = (float)r;
        float m  = (r < ci) ? (1.f - jf / c) : (-(jf - c + 1.f) / (nc - c));
        sum += d2 * m * m;
    }

    for (int off = 32; off > 0; off >>= 1) sum += __shfl_down(sum, off);
    int lane = tid & 63, wave = tid >> 6;
    if (lane == 0) wsum[wave] = sum;
    __syncthreads();
    if (tid == 0) {
        float t = wsum[0] + wsum[1] + wsum[2] + wsum[3];
        atomicAdd(out, t * (1.f / ((float)B2 * (float)B2)));
    }
}

extern "C" void kernel_launch(void* const* d_in, const int* in_sizes, int n_in,
                              void* d_out, int out_size, void* d_ws, size_t ws_size,
                              hipStream_t stream) {
    const float* X       = (const float*)d_in[0];
    const int*   ranking = (const int*)d_in[1];
    const int*   choice  = (const int*)d_in[2];
    const int*   ncp     = (const int*)d_in[3];
    float*       ws      = (float*)d_ws;

    // ws layout: C (512*512 f32 = 1 MB) | partials (255 * 64K bf16 = 33.4 MB)
    float*  C        = ws;
    __bf16* partials = (__bf16*)(ws + 262144);

    hipMemsetAsync(d_out, 0, sizeof(float), stream);

    gemm_partial<<<dim3(NBLK), dim3(512), 0, stream>>>(X, partials);
    reduce_partials<<<dim3(3 * 16384 / 256), dim3(256), 0, stream>>>(partials, C);
    loss_kernel<<<dim3(B2), dim3(256), 0, stream>>>(C, ranking, choice, ncp, (float*)d_out);
}